// Round 8
// baseline (257.108 us; speedup 1.0000x reference)
//
#include <hip/hip_runtime.h>

// MSE over remapped (norms, labels):
//   label==1: n *= 10, target = 10
//   label==2: n *= 5,  target = 20
//   else:     n *= 1,  target = 0
// out[0] = mean((n - target)^2) over 4096*8192 f32 elements.
//
// Ladder: naive 105us -> x4 unroll 101us -> +nontemporal ~80us (nt bypasses
// L1-allocate; round 5) -> x8 unroll flat (MLP not binding; round 6).
// This round: kill the 2048-same-address atomicAdd tail via two-stage
// reduction (block partials to d_ws, tiny second kernel sums).

typedef float f4 __attribute__((ext_vector_type(4)));

#define NBLOCKS 2048

__device__ __forceinline__ float remap_sq(float n, float lab) {
    float sn  = (lab == 1.0f) ? 10.0f : ((lab == 2.0f) ? 5.0f : 1.0f);
    float tgt = lab * 10.0f;                 // 0 / 10 / 20
    float d   = fmaf(n, sn, -tgt);
    return d * d;
}

__device__ __forceinline__ float remap_sq4(f4 n, f4 l) {
    return remap_sq(n.x, l.x) + remap_sq(n.y, l.y)
         + remap_sq(n.z, l.z) + remap_sq(n.w, l.w);
}

__global__ __launch_bounds__(256) void mse_remap_stage1(
    const float* __restrict__ norms,
    const float* __restrict__ labels,
    float* __restrict__ partials,        // d_ws, one slot per block
    size_t n4, size_t n)
{
    const f4* np4 = reinterpret_cast<const f4*>(norms);
    const f4* lp4 = reinterpret_cast<const f4*>(labels);

    size_t tid    = (size_t)blockIdx.x * blockDim.x + threadIdx.x;
    size_t stride = (size_t)gridDim.x * blockDim.x;

    float acc = 0.0f;
    size_t i = tid;

    // 8 stride-points/iter, 16 nt float4 loads batched (256 B/lane in flight).
    for (; i + 7 * stride < n4; i += 8 * stride) {
        f4 a0 = __builtin_nontemporal_load(&np4[i]);
        f4 a1 = __builtin_nontemporal_load(&np4[i +     stride]);
        f4 a2 = __builtin_nontemporal_load(&np4[i + 2 * stride]);
        f4 a3 = __builtin_nontemporal_load(&np4[i + 3 * stride]);
        f4 a4 = __builtin_nontemporal_load(&np4[i + 4 * stride]);
        f4 a5 = __builtin_nontemporal_load(&np4[i + 5 * stride]);
        f4 a6 = __builtin_nontemporal_load(&np4[i + 6 * stride]);
        f4 a7 = __builtin_nontemporal_load(&np4[i + 7 * stride]);
        f4 b0 = __builtin_nontemporal_load(&lp4[i]);
        f4 b1 = __builtin_nontemporal_load(&lp4[i +     stride]);
        f4 b2 = __builtin_nontemporal_load(&lp4[i + 2 * stride]);
        f4 b3 = __builtin_nontemporal_load(&lp4[i + 3 * stride]);
        f4 b4 = __builtin_nontemporal_load(&lp4[i + 4 * stride]);
        f4 b5 = __builtin_nontemporal_load(&lp4[i + 5 * stride]);
        f4 b6 = __builtin_nontemporal_load(&lp4[i + 6 * stride]);
        f4 b7 = __builtin_nontemporal_load(&lp4[i + 7 * stride]);
        acc += remap_sq4(a0, b0);
        acc += remap_sq4(a1, b1);
        acc += remap_sq4(a2, b2);
        acc += remap_sq4(a3, b3);
        acc += remap_sq4(a4, b4);
        acc += remap_sq4(a5, b5);
        acc += remap_sq4(a6, b6);
        acc += remap_sq4(a7, b7);
    }
    // float4 remainder (not hit at this size — defensive)
    for (; i < n4; i += stride) {
        f4 a = __builtin_nontemporal_load(&np4[i]);
        f4 b = __builtin_nontemporal_load(&lp4[i]);
        acc += remap_sq4(a, b);
    }
    // scalar remainder (defensive only)
    for (size_t j = n4 * 4 + tid; j < n; j += stride)
        acc += remap_sq(norms[j], labels[j]);

    // wave-64 butterfly reduction
#pragma unroll
    for (int off = 32; off > 0; off >>= 1)
        acc += __shfl_down(acc, off, 64);

    __shared__ float wsum[4];                // 256 threads = 4 waves
    int lane = threadIdx.x & 63;
    int wid  = threadIdx.x >> 6;
    if (lane == 0) wsum[wid] = acc;
    __syncthreads();

    if (threadIdx.x == 0) {
        // one uncontended global store per block (no atomics)
        partials[blockIdx.x] = (wsum[0] + wsum[1]) + (wsum[2] + wsum[3]);
    }
}

__global__ __launch_bounds__(256) void mse_remap_stage2(
    const float* __restrict__ partials,
    float* __restrict__ out, float inv_n)
{
    // NBLOCKS=2048 floats = 512 float4; 256 threads x 2 float4 each.
    const f4* p4 = reinterpret_cast<const f4*>(partials);
    f4 v0 = p4[threadIdx.x];
    f4 v1 = p4[threadIdx.x + 256];
    float acc = (v0.x + v0.y) + (v0.z + v0.w)
              + (v1.x + v1.y) + (v1.z + v1.w);

#pragma unroll
    for (int off = 32; off > 0; off >>= 1)
        acc += __shfl_down(acc, off, 64);

    __shared__ float wsum[4];
    int lane = threadIdx.x & 63;
    int wid  = threadIdx.x >> 6;
    if (lane == 0) wsum[wid] = acc;
    __syncthreads();

    if (threadIdx.x == 0)
        out[0] = ((wsum[0] + wsum[1]) + (wsum[2] + wsum[3])) * inv_n;
}

extern "C" void kernel_launch(void* const* d_in, const int* in_sizes, int n_in,
                              void* d_out, int out_size, void* d_ws, size_t ws_size,
                              hipStream_t stream)
{
    const float* norms  = (const float*)d_in[0];
    const float* labels = (const float*)d_in[1];
    float* out      = (float*)d_out;
    float* partials = (float*)d_ws;          // 2048 floats = 8 KB scratch

    size_t n  = (size_t)in_sizes[0];         // 4096*8192 = 33,554,432
    size_t n4 = n / 4;
    float inv_n = 1.0f / (float)n;

    mse_remap_stage1<<<NBLOCKS, 256, 0, stream>>>(norms, labels, partials, n4, n);
    mse_remap_stage2<<<1, 256, 0, stream>>>(partials, out, inv_n);
}

// Round 9
// 250.614 us; speedup vs baseline: 1.0259x; 1.0259x over previous
//
#include <hip/hip_runtime.h>

// MSE over remapped (norms, labels):
//   label==1: n *= 10, target = 10
//   label==2: n *= 5,  target = 20
//   else:     n *= 1,  target = 0
// out[0] = mean((n - target)^2) over 4096*8192 f32 elements.
//
// Ladder: naive grid-stride 105us -> x4 unroll 101us -> +nontemporal ~84us
// -> x8 unroll flat -> two-stage reduction flat (atomics not a cost).
// Kernel reads 268MB at ~3.2 TB/s vs 6.9 TB/s fill-write on same chip.
// This round: contiguous per-block chunks (sequential sweep, nt loads) to
// restore DRAM row-buffer locality that 8MB-stride grid-striding destroys.

typedef float f4 __attribute__((ext_vector_type(4)));

#define NBLOCKS 2048
#define NTHREADS 256

__device__ __forceinline__ float remap_sq(float n, float lab) {
    float sn  = (lab == 1.0f) ? 10.0f : ((lab == 2.0f) ? 5.0f : 1.0f);
    float tgt = lab * 10.0f;                 // 0 / 10 / 20
    float d   = fmaf(n, sn, -tgt);
    return d * d;
}

__device__ __forceinline__ float remap_sq4(f4 n, f4 l) {
    return remap_sq(n.x, l.x) + remap_sq(n.y, l.y)
         + remap_sq(n.z, l.z) + remap_sq(n.w, l.w);
}

__global__ __launch_bounds__(NTHREADS) void mse_remap_stage1(
    const float* __restrict__ norms,
    const float* __restrict__ labels,
    float* __restrict__ partials,        // d_ws, one slot per block
    size_t n4, size_t n, size_t chunk)   // chunk = f4 elements per block
{
    const f4* np4 = reinterpret_cast<const f4*>(norms);
    const f4* lp4 = reinterpret_cast<const f4*>(labels);

    size_t base = (size_t)blockIdx.x * chunk;
    size_t end  = base + chunk; if (end > n4) end = n4;

    float acc = 0.0f;
    size_t i = base + threadIdx.x;

    // Batch 8 block-iterations: 16 nt float4 loads in flight, spanning a
    // contiguous 32KB window per array -> DRAM row-buffer friendly.
    for (; i + 7 * NTHREADS < end; i += 8 * NTHREADS) {
        f4 a0 = __builtin_nontemporal_load(&np4[i]);
        f4 a1 = __builtin_nontemporal_load(&np4[i + 1 * NTHREADS]);
        f4 a2 = __builtin_nontemporal_load(&np4[i + 2 * NTHREADS]);
        f4 a3 = __builtin_nontemporal_load(&np4[i + 3 * NTHREADS]);
        f4 a4 = __builtin_nontemporal_load(&np4[i + 4 * NTHREADS]);
        f4 a5 = __builtin_nontemporal_load(&np4[i + 5 * NTHREADS]);
        f4 a6 = __builtin_nontemporal_load(&np4[i + 6 * NTHREADS]);
        f4 a7 = __builtin_nontemporal_load(&np4[i + 7 * NTHREADS]);
        f4 b0 = __builtin_nontemporal_load(&lp4[i]);
        f4 b1 = __builtin_nontemporal_load(&lp4[i + 1 * NTHREADS]);
        f4 b2 = __builtin_nontemporal_load(&lp4[i + 2 * NTHREADS]);
        f4 b3 = __builtin_nontemporal_load(&lp4[i + 3 * NTHREADS]);
        f4 b4 = __builtin_nontemporal_load(&lp4[i + 4 * NTHREADS]);
        f4 b5 = __builtin_nontemporal_load(&lp4[i + 5 * NTHREADS]);
        f4 b6 = __builtin_nontemporal_load(&lp4[i + 6 * NTHREADS]);
        f4 b7 = __builtin_nontemporal_load(&lp4[i + 7 * NTHREADS]);
        acc += remap_sq4(a0, b0);
        acc += remap_sq4(a1, b1);
        acc += remap_sq4(a2, b2);
        acc += remap_sq4(a3, b3);
        acc += remap_sq4(a4, b4);
        acc += remap_sq4(a5, b5);
        acc += remap_sq4(a6, b6);
        acc += remap_sq4(a7, b7);
    }
    // f4 remainder within chunk (not hit at this size — defensive)
    for (; i < end; i += NTHREADS) {
        f4 a = __builtin_nontemporal_load(&np4[i]);
        f4 b = __builtin_nontemporal_load(&lp4[i]);
        acc += remap_sq4(a, b);
    }
    // scalar global remainder (n % 4 != 0 — defensive, block 0 only)
    if (blockIdx.x == 0)
        for (size_t j = n4 * 4 + threadIdx.x; j < n; j += NTHREADS)
            acc += remap_sq(norms[j], labels[j]);

    // wave-64 butterfly reduction
#pragma unroll
    for (int off = 32; off > 0; off >>= 1)
        acc += __shfl_down(acc, off, 64);

    __shared__ float wsum[4];                // 256 threads = 4 waves
    int lane = threadIdx.x & 63;
    int wid  = threadIdx.x >> 6;
    if (lane == 0) wsum[wid] = acc;
    __syncthreads();

    if (threadIdx.x == 0)
        partials[blockIdx.x] = (wsum[0] + wsum[1]) + (wsum[2] + wsum[3]);
}

__global__ __launch_bounds__(NTHREADS) void mse_remap_stage2(
    const float* __restrict__ partials,
    float* __restrict__ out, float inv_n)
{
    // NBLOCKS=2048 floats = 512 float4; 256 threads x 2 float4 each.
    const f4* p4 = reinterpret_cast<const f4*>(partials);
    f4 v0 = p4[threadIdx.x];
    f4 v1 = p4[threadIdx.x + 256];
    float acc = (v0.x + v0.y) + (v0.z + v0.w)
              + (v1.x + v1.y) + (v1.z + v1.w);

#pragma unroll
    for (int off = 32; off > 0; off >>= 1)
        acc += __shfl_down(acc, off, 64);

    __shared__ float wsum[4];
    int lane = threadIdx.x & 63;
    int wid  = threadIdx.x >> 6;
    if (lane == 0) wsum[wid] = acc;
    __syncthreads();

    if (threadIdx.x == 0)
        out[0] = ((wsum[0] + wsum[1]) + (wsum[2] + wsum[3])) * inv_n;
}

extern "C" void kernel_launch(void* const* d_in, const int* in_sizes, int n_in,
                              void* d_out, int out_size, void* d_ws, size_t ws_size,
                              hipStream_t stream)
{
    const float* norms  = (const float*)d_in[0];
    const float* labels = (const float*)d_in[1];
    float* out      = (float*)d_out;
    float* partials = (float*)d_ws;          // 2048 floats = 8 KB scratch

    size_t n  = (size_t)in_sizes[0];         // 4096*8192 = 33,554,432
    size_t n4 = n / 4;                       // 8,388,608 f4
    size_t chunk = (n4 + NBLOCKS - 1) / NBLOCKS;   // 4096 f4 = 64 KB per block
    float inv_n = 1.0f / (float)n;

    mse_remap_stage1<<<NBLOCKS, NTHREADS, 0, stream>>>(norms, labels, partials,
                                                       n4, n, chunk);
    mse_remap_stage2<<<1, NTHREADS, 0, stream>>>(partials, out, inv_n);
}